// Round 7
// baseline (15.662 us; speedup 1.0000x reference)
//
#include <hip/hip_runtime.h>
#include <math.h>

#define BLOCK 256
#define TPT 2   // tokens per thread; block covers 512 tokens = 1024 float4 slots

typedef float v4f __attribute__((ext_vector_type(4)));

// Even/odd-parity partial products monoid for type-2 roots.
struct EO { float E, O; };
__device__ __forceinline__ EO mergeEO(EO a, EO b) {
    EO r;
    r.E = fmaf(a.E, b.E, a.O * b.O);
    r.O = fmaf(a.E, b.O, a.O * b.E);
    return r;
}

// weights = softmax(20 * x.r) over 240 unit-norm E8 roots, closed form (O(8)):
//  Type-1 (112): rank-1 factorization A=u+v, B=u-v, u=s*g^2, v=s*h^2
//  Type-2 (128): even-parity monoid over (g,h)
//  g/h = exp2(+-K2*x_j - C/8), s = exp2(-C/4), C = (20/ln2)*|x| (all exps <= 0).
__device__ __forceinline__ void e8q_token(const float xs[8], float o[8]) {
    float n2 = 0.0f;
#pragma unroll
    for (int j = 0; j < 8; ++j) n2 = fmaf(xs[j], xs[j], n2);
    const float xn = __builtin_amdgcn_sqrtf(n2);

    const float K2 = 10.201358186637847f;       // (20/ln2)/(2*sqrt(2))
    const float C  = 28.853900817779268f * xn;  // (20/ln2)*|x|
    const float Ce = 0.125f * C;
    const float s  = __builtin_amdgcn_exp2f(-0.25f * C);

    float A[8], B[8], g[8], h[8];
#pragma unroll
    for (int j = 0; j < 8; ++j) {
        g[j] = __builtin_amdgcn_exp2f(fmaf(K2, xs[j], -Ce));
        h[j] = __builtin_amdgcn_exp2f(fmaf(-K2, xs[j], -Ce));
        float a = g[j] * g[j];
        float b = h[j] * h[j];
        float sa = s * a;                // u_j
        A[j] = fmaf(s, b, sa);           // u + v
        B[j] = fmaf(-s, b, sa);          // u - v
    }

    // Type-1: exclude-one sums via prefix+suffix adds (no cancelling subtraction)
    float preA[8], sufA[8];
    preA[0] = A[0];
#pragma unroll
    for (int j = 1; j < 8; ++j) preA[j] = preA[j - 1] + A[j];
    sufA[7] = A[7];
#pragma unroll
    for (int j = 6; j >= 0; --j) sufA[j] = sufA[j + 1] + A[j];

    float EA[8];
    EA[0] = sufA[1];
    EA[7] = preA[6];
#pragma unroll
    for (int j = 1; j < 7; ++j) EA[j] = preA[j - 1] + sufA[j + 1];

    float s1 = 0.0f;
#pragma unroll
    for (int j = 0; j < 7; ++j) s1 = fmaf(A[j], sufA[j + 1], s1);

    // Type-2: parity monoid prefix/suffix
    EO pre[8], suf[8];
    pre[0] = {g[0], h[0]};
#pragma unroll
    for (int j = 1; j < 8; ++j) pre[j] = mergeEO(pre[j - 1], {g[j], h[j]});
    suf[7] = {g[7], h[7]};
#pragma unroll
    for (int j = 6; j >= 1; --j) suf[j] = mergeEO({g[j], h[j]}, suf[j + 1]);

    const float s2 = pre[7].E;

    EO ex[8];
    ex[0] = suf[1];
    ex[7] = pre[6];
#pragma unroll
    for (int j = 1; j < 7; ++j) ex[j] = mergeEO(pre[j - 1], suf[j + 1]);

    const float inv = __builtin_amdgcn_rcpf(s1 + s2);
    const float c1 = 0.70710678118654752f * inv;   // 1/sqrt2
    const float c2 = 0.35355339059327376f * inv;   // 1/(2*sqrt2)

#pragma unroll
    for (int j = 0; j < 8; ++j) {
        float t1 = B[j] * EA[j];
        float t2 = fmaf(g[j], ex[j].E, -(h[j] * ex[j].O));
        o[j] = fmaf(c1, t1, c2 * t2);
    }
}

__global__ __launch_bounds__(BLOCK, 4) void e8q_kernel(const float* __restrict__ x,
                                                       float* __restrict__ out) {
    // Parity-split staging: region A holds even float4-slots (first half of each
    // token), region B the odd slots. Both the dense-side and token-side accesses
    // are perfectly bank-balanced (8 accesses/bank on an 8-cycle-minimum b128 op).
    __shared__ v4f inA[BLOCK * TPT];
    __shared__ v4f inB[BLOCK * TPT];
    __shared__ v4f outA[BLOCK * TPT];
    __shared__ v4f outB[BLOCK * TPT];

    const int tid = threadIdx.x;
    const size_t tok0 = (size_t)blockIdx.x * (BLOCK * TPT);
    const v4f* xv = (const v4f*)x + tok0 * 2;

    // Phase 1: dense global loads (each instruction covers contiguous 1KB/wave),
    // scatter to parity-split LDS. All 4 loads issued up front for MLP.
    v4f ld[2 * TPT];
#pragma unroll
    for (int k = 0; k < 2 * TPT; ++k) ld[k] = xv[k * BLOCK + tid];
#pragma unroll
    for (int k = 0; k < 2 * TPT; ++k) {
        const int s = k * BLOCK + tid;
        ((s & 1) ? inB : inA)[s >> 1] = ld[k];
    }

    __syncthreads();

    // Phase 2: token-major readback, compute, stage results.
#pragma unroll
    for (int p = 0; p < TPT; ++p) {
        const int t = tid + p * BLOCK;
        v4f a = inA[t];
        v4f b = inB[t];
        float xs[8] = {a.x, a.y, a.z, a.w, b.x, b.y, b.z, b.w};
        float o[8];
        e8q_token(xs, o);
        outA[t] = (v4f){o[0], o[1], o[2], o[3]};
        outB[t] = (v4f){o[4], o[5], o[6], o[7]};
    }

    __syncthreads();

    // Phase 3: dense flush (lane-contiguous float4 slots -> full lines).
    v4f* outp = (v4f*)out + tok0 * 2;
#pragma unroll
    for (int k = 0; k < 2 * TPT; ++k) {
        const int s = k * BLOCK + tid;
        v4f val = ((s & 1) ? outB : outA)[s >> 1];
        __builtin_nontemporal_store(val, outp + s);
    }
}

extern "C" void kernel_launch(void* const* d_in, const int* in_sizes, int n_in,
                              void* d_out, int out_size, void* d_ws, size_t ws_size,
                              hipStream_t stream) {
    const float* x = (const float*)d_in[0];
    float* out = (float*)d_out;

    const int tokens = in_sizes[0] / 8;        // 1,048,576
    const int grid = tokens / (BLOCK * TPT);   // 2048

    e8q_kernel<<<grid, BLOCK, 0, stream>>>(x, out);
}

// Round 9
// 14.917 us; speedup vs baseline: 1.0499x; 1.0499x over previous
//
#include <hip/hip_runtime.h>
#include <math.h>

#define BLOCK 256

typedef float v4f __attribute__((ext_vector_type(4)));

// Even/odd-parity partial sums monoid for type-2 roots. E and O are sums of
// POSITIVE partial weight-products of actual parity classes — every
// intermediate is bounded by the softmax denominator (numerically safe).
// (The Π(g±h) product shortcut is NOT safe: it mixes in odd-parity phantom
// patterns that can exceed the denominator by ~2^40 and cancel destructively.)
struct EO { float E, O; };
__device__ __forceinline__ EO mergeEO(EO a, EO b) {
    EO r;
    r.E = fmaf(a.E, b.E, a.O * b.O);
    r.O = fmaf(a.E, b.O, a.O * b.E);
    return r;
}

// weights = softmax(20 * x.r) over 240 unit-norm E8 roots, closed form (O(8)):
//  Type-1 (112): rank-1 factorization A=u+v, B=u-v, u=s*g^2, v=s*h^2
//  Type-2 (128): even-parity monoid over (g,h)
//  g/h = exp2(+-K2*x_j - C/8), s = exp2(-C/4), C = (20/ln2)*|x| (all exps <= 0).
__device__ __forceinline__ void e8q_token(const float xs[8], float o[8]) {
    float n2 = 0.0f;
#pragma unroll
    for (int j = 0; j < 8; ++j) n2 = fmaf(xs[j], xs[j], n2);
    const float xn = __builtin_amdgcn_sqrtf(n2);

    const float K2 = 10.201358186637847f;       // (20/ln2)/(2*sqrt(2))
    const float C  = 28.853900817779268f * xn;  // (20/ln2)*|x|
    const float Ce = 0.125f * C;
    const float s  = __builtin_amdgcn_exp2f(-0.25f * C);

    float A[8], B[8], g[8], h[8];
#pragma unroll
    for (int j = 0; j < 8; ++j) {
        g[j] = __builtin_amdgcn_exp2f(fmaf(K2, xs[j], -Ce));
        h[j] = __builtin_amdgcn_exp2f(fmaf(-K2, xs[j], -Ce));
        float a = g[j] * g[j];
        float b = h[j] * h[j];
        float sa = s * a;                // u_j
        A[j] = fmaf(s, b, sa);           // u + v
        B[j] = fmaf(-s, b, sa);          // u - v
    }

    // Suffix arrays only; prefixes are walked incrementally in the final loop
    // (saves ~30 live VGPRs vs materializing pre[]/ex[]).
    float sufA[8];
    sufA[7] = A[7];
#pragma unroll
    for (int j = 6; j >= 0; --j) sufA[j] = sufA[j + 1] + A[j];

    float s1 = 0.0f;   // sum_{i<j} A_i A_j (all 112 type-1 weights; positive adds)
#pragma unroll
    for (int j = 0; j < 7; ++j) s1 = fmaf(A[j], sufA[j + 1], s1);

    EO suf[8];
    suf[7] = {g[7], h[7]};
#pragma unroll
    for (int j = 6; j >= 1; --j) suf[j] = mergeEO({g[j], h[j]}, suf[j + 1]);

    const float s2 = mergeEO({g[0], h[0]}, suf[1]).E;  // all 128 even-parity weights

    const float inv = __builtin_amdgcn_rcpf(s1 + s2);
    const float c1 = 0.70710678118654752f * inv;   // 1/sqrt2
    const float c2 = 0.35355339059327376f * inv;   // 1/(2*sqrt2)

    // Final combine with running prefix (type-1 scalar, type-2 monoid).
    float preA = 0.0f;
    EO preEO;
#pragma unroll
    for (int j = 0; j < 8; ++j) {
        float EA;
        EO ex;
        if (j == 0) {
            EA = sufA[1];
            ex = suf[1];
        } else if (j == 7) {
            EA = preA;
            ex = preEO;
        } else {
            EA = preA + sufA[j + 1];
            ex = mergeEO(preEO, suf[j + 1]);
        }
        float t2 = fmaf(g[j], ex.E, -(h[j] * ex.O));
        o[j] = fmaf(c1 * B[j], EA, c2 * t2);

        if (j == 0) {
            preA = A[0];
            preEO = {g[0], h[0]};
        } else {
            preA += A[j];
            preEO = mergeEO(preEO, {g[j], h[j]});
        }
    }
}

__global__ __launch_bounds__(BLOCK, 6) void e8q_kernel(const float* __restrict__ x,
                                                       float* __restrict__ out) {
    // Output staged through parity-split LDS so every global store is lane-dense
    // (R6's proven win). Input loads stay strided: L1 merges the half-line pairs
    // and each thread's compute starts as soon as its own loads land.
    __shared__ v4f lA[BLOCK];
    __shared__ v4f lB[BLOCK];

    const int tid = threadIdx.x;
    const size_t tok0 = (size_t)blockIdx.x * BLOCK;

    const v4f* xp = (const v4f*)(x + (tok0 + tid) * 8);
    v4f a = xp[0];
    v4f b = xp[1];
    float xs[8] = {a.x, a.y, a.z, a.w, b.x, b.y, b.z, b.w};

    float o[8];
    e8q_token(xs, o);

    lA[tid] = (v4f){o[0], o[1], o[2], o[3]};
    lB[tid] = (v4f){o[4], o[5], o[6], o[7]};

    __syncthreads();

    // Dense flush: lane-contiguous float4 slots -> fully-covered cache lines.
    v4f* outp = (v4f*)out + tok0 * 2;
#pragma unroll
    for (int k = 0; k < 2; ++k) {
        const int sidx = k * BLOCK + tid;
        v4f val = ((sidx & 1) ? lB : lA)[sidx >> 1];
        __builtin_nontemporal_store(val, outp + sidx);
    }
}

extern "C" void kernel_launch(void* const* d_in, const int* in_sizes, int n_in,
                              void* d_out, int out_size, void* d_ws, size_t ws_size,
                              hipStream_t stream) {
    const float* x = (const float*)d_in[0];
    float* out = (float*)d_out;

    const int tokens = in_sizes[0] / 8;   // 1,048,576
    const int grid = tokens / BLOCK;      // 4096

    e8q_kernel<<<grid, BLOCK, 0, stream>>>(x, out);
}